// Round 7
// baseline (377.502 us; speedup 1.0000x reference)
//
#include <hip/hip_runtime.h>
#include <hip/hip_bf16.h>

typedef __hip_bfloat16 bf16;
typedef __attribute__((ext_vector_type(8))) short short8;   // MFMA A/B frag (8 bf16)
typedef __attribute__((ext_vector_type(4))) float floatx4;  // MFMA C/D frag
typedef __attribute__((ext_vector_type(4))) short s16x4;

#define NE 524288
#define NA 16384
#define E  64        // edges per block (edge kernel)
#define AG 32        // agents per block (agent kernel)
#define S1 260       // LDS act row stride (shorts)
#define SH3 68       // h3 overlay row stride (floats), inside wave's own quarter

__device__ __forceinline__ float ld(const void* p, long i, int f32) {
    return f32 ? ((const float*)p)[i] : __bfloat162float(((const bf16*)p)[i]);
}
__device__ __forceinline__ short f2bs(float f) {
    bf16 h = __float2bfloat16(f);
    return *(short*)&h;
}
__device__ __forceinline__ float bs2f(short s) {
    union { unsigned u; float f; } c;
    c.u = ((unsigned)(unsigned short)s) << 16;
    return c.f;
}
// pack 2 floats -> 2 bf16 in one dword (a = low/even n, b = high/odd n)
__device__ __forceinline__ unsigned pk(float a, float b) {
    return ((unsigned)(unsigned short)f2bs(b) << 16) | (unsigned)(unsigned short)f2bs(a);
}

// ---------------------------------------------------------------------------
// Weight prep (dtype detector fused in): bf16-ize + transpose GEMM weights to
// n-major [n][k]; Wp1Tp zero-padded to K=32. Biases + Wr3 to f32.
// ---------------------------------------------------------------------------
__global__ void prep_weights_kernel(
    const void* __restrict__ Wp1, const void* __restrict__ bp1,
    const void* __restrict__ Wp2, const void* __restrict__ bp2,
    const void* __restrict__ Wp3, const void* __restrict__ bp3,
    const void* __restrict__ Wr1, const void* __restrict__ br1,
    const void* __restrict__ Wr2, const void* __restrict__ br2,
    const void* __restrict__ Wr3, const void* __restrict__ br3,
    short* __restrict__ Wp1Tp, short* __restrict__ Wp2T, short* __restrict__ Wp3T,
    short* __restrict__ Wr1T,  short* __restrict__ Wr2T,
    float* __restrict__ bp1f, float* __restrict__ bp2f, float* __restrict__ bp3f,
    float* __restrict__ br1f, float* __restrict__ br2f,
    float* __restrict__ Wr3f, float* __restrict__ br3f,
    int* __restrict__ flag)
{
    __shared__ int sflag;
    if (threadIdx.x < 64) {
        const unsigned short* w = (const unsigned short*)Wp2;
        int bad = 0;
        for (int i = threadIdx.x; i < 1024; i += 64) {
            const int e = (w[i] >> 7) & 0xFF;
            if (e >= 131) bad = 1;                // |v|>=16 / inf / nan -> f32 bits
        }
        const unsigned long long m = __ballot(bad);
        if (threadIdx.x == 0) {
            sflag = (m != 0ull) ? 1 : 0;
            if (blockIdx.x == 0) *flag = sflag;
        }
    }
    __syncthreads();
    const int f32 = sflag;

    const int stride = gridDim.x * blockDim.x;
    for (int i = blockIdx.x * blockDim.x + threadIdx.x; i < 173634; i += stride) {
        if (i < 65536) {                       // Wp2T[n][k] = Wp2[k][n]
            const int n = i >> 8, k = i & 255;
            Wp2T[i] = f2bs(ld(Wp2, (long)k * 256 + n, f32));
        } else if (i < 81920) {                // Wp3T[n][k] = Wp3[k][n]
            const int j = i - 65536, n = j >> 8, k = j & 255;
            Wp3T[j] = f2bs(ld(Wp3, (long)k * 64 + n, f32));
        } else if (i < 90112) {                // Wp1Tp[n][k<32], zero-pad k>=4
            const int j = i - 81920, n = j >> 5, k = j & 31;
            Wp1Tp[j] = (k < 4) ? f2bs(ld(Wp1, (long)k * 256 + n, f32)) : (short)0;
        } else if (i < 106496) {               // Wr1T[n][k=64]
            const int j = i - 90112, n = j >> 6, k = j & 63;
            Wr1T[j] = f2bs(ld(Wr1, (long)k * 256 + n, f32));
        } else if (i < 172032) {               // Wr2T[n][k=256]
            const int j = i - 106496, n = j >> 8, k = j & 255;
            Wr2T[j] = f2bs(ld(Wr2, (long)k * 256 + n, f32));
        } else if (i < 172288) { bp1f[i - 172032] = ld(bp1, i - 172032, f32); }
        else if (i < 172544) { bp2f[i - 172288] = ld(bp2, i - 172288, f32); }
        else if (i < 172608) { bp3f[i - 172544] = ld(bp3, i - 172544, f32); }
        else if (i < 172864) { br1f[i - 172608] = ld(br1, i - 172608, f32); }
        else if (i < 173120) { br2f[i - 172864] = ld(br2, i - 172864, f32); }
        else if (i < 173632) { Wr3f[i - 173120] = ld(Wr3, i - 173120, f32); }
        else                 { br3f[i - 173632] = ld(br3, i - 173632, f32); }
    }
}

// ---------------------------------------------------------------------------
// Edge MLP, all-MFMA, swapped operands (weights=A, acts=B). 64 edges/block.
// R7: latency scheduling — all independent global loads issued at the top,
// L3 K-loop gets lookahead-1 weight prefetch (initial frags + bias issued
// before the L2-epilogue barriers), scatter gathers LDS reads into regs.
// ---------------------------------------------------------------------------
__global__ __launch_bounds__(256, 4) void edge_mlp_kernel(
    const void* __restrict__ ef, const int* __restrict__ ids,
    const short* __restrict__ Wp1Tp, const float* __restrict__ bp1f,
    const short* __restrict__ Wp2T, const float* __restrict__ bp2f,
    const short* __restrict__ Wp3T, const float* __restrict__ bp3f,
    float* __restrict__ agg, float* __restrict__ bar,
    const int* __restrict__ flag)
{
    __shared__ __align__(16) short hs[E * S1];     // 33.3 KB: h1, h2, then h3 overlay
    __shared__ float cb[E][2];
    __shared__ int   sid[E];

    const int t = threadIdx.x;
    const long e0 = (long)blockIdx.x * E;
    const int f32 = *flag;
    const int wave = t >> 6, lane = t & 63, quad = lane >> 4, ln = lane & 15;
    const int nb = wave * 64;

    // ======== kernel-top: issue ALL independent global loads ========
    short8 w1[4];                        // L1 A-frags (weights)
    #pragma unroll
    for (int nt = 0; nt < 4; ++nt)
        w1[nt] = *(const short8*)&Wp1Tp[(nb + nt * 16 + ln) * 32 + quad * 8];
    float4 b1[4], b2[4];                 // L1/L2 biases
    #pragma unroll
    for (int nt = 0; nt < 4; ++nt) {
        b1[nt] = *(const float4*)&bp1f[nb + nt * 16 + quad * 4];
        b2[nt] = *(const float4*)&bp2f[nb + nt * 16 + quad * 4];
    }
    short8 wcur[4];                      // L2 ks=0 weights
    #pragma unroll
    for (int nt = 0; nt < 4; ++nt)
        wcur[nt] = *(const short8*)&Wp2T[(nb + nt * 16 + ln) * 256 + quad * 8];
    short8 xb[4];                        // B-frags: edge features (quad 0 holds k<4)
    #pragma unroll
    for (int mt = 0; mt < 4; ++mt) {
        short8 v = {};
        if (quad == 0) {
            const long e = e0 + mt * 16 + ln;
            if (f32) {
                const float4 x = ((const float4*)ef)[e];
                v[0] = f2bs(x.x); v[1] = f2bs(x.y); v[2] = f2bs(x.z); v[3] = f2bs(x.w);
            } else {
                const int2 x = ((const int2*)ef)[e];
                v[0] = (short)(x.x & 0xffff); v[1] = (short)((unsigned)x.x >> 16);
                v[2] = (short)(x.y & 0xffff); v[3] = (short)((unsigned)x.y >> 16);
            }
        }
        xb[mt] = v;
    }
    if (t < E) {
        sid[t] = ids[e0 + t];
        const float px = ld(ef, (e0 + t) * 4 + 0, f32);
        const float py = ld(ef, (e0 + t) * 4 + 1, f32);
        const float d = sqrtf(px * px + py * py);
        const float inv = 1.0f / (d * (d - 0.18f));
        cb[t][0] = -px * inv;
        cb[t][1] = -py * inv;
    }

    // ---- layer 1: h1 = relu(x @ Wp1 + bp1) ----
    {
        floatx4 acc[4][4];
        #pragma unroll
        for (int nt = 0; nt < 4; ++nt) {
            const floatx4 bi = { b1[nt].x, b1[nt].y, b1[nt].z, b1[nt].w };
            #pragma unroll
            for (int mt = 0; mt < 4; ++mt) acc[mt][nt] = bi;
        }
        #pragma unroll
        for (int nt = 0; nt < 4; ++nt)
            #pragma unroll
            for (int mt = 0; mt < 4; ++mt)
                acc[mt][nt] = __builtin_amdgcn_mfma_f32_16x16x32_bf16(w1[nt], xb[mt], acc[mt][nt], 0, 0, 0);
        #pragma unroll
        for (int mt = 0; mt < 4; ++mt)
            #pragma unroll
            for (int nt = 0; nt < 4; ++nt) {
                const floatx4 v = acc[mt][nt];
                uint2 w;
                w.x = pk(fmaxf(v[0], 0.f), fmaxf(v[1], 0.f));
                w.y = pk(fmaxf(v[2], 0.f), fmaxf(v[3], 0.f));
                *(uint2*)&hs[(mt * 16 + ln) * S1 + nb + nt * 16 + quad * 4] = w;
            }
    }
    __syncthreads();

    // ---- layer 2: h2 = relu(h1 @ Wp2 + bp2); lookahead-1 weight prefetch ----
    short8 v3cur[4];     // L3 ks=0 weights (issued before the epilogue barriers)
    float4 b3;           // L3 bias
    {
        floatx4 acc[4][4];
        #pragma unroll
        for (int nt = 0; nt < 4; ++nt) {
            const floatx4 bi = { b2[nt].x, b2[nt].y, b2[nt].z, b2[nt].w };
            #pragma unroll
            for (int mt = 0; mt < 4; ++mt) acc[mt][nt] = bi;
        }
        short8 wnxt[4];
        #pragma unroll
        for (int ks = 0; ks < 8; ++ks) {
            if (ks < 7) {
                #pragma unroll
                for (int nt = 0; nt < 4; ++nt)
                    wnxt[nt] = *(const short8*)&Wp2T[(nb + nt * 16 + ln) * 256 + (ks + 1) * 32 + quad * 8];
            }
            short8 b[4];
            #pragma unroll
            for (int mt = 0; mt < 4; ++mt)
                b[mt] = *(const short8*)&hs[(mt * 16 + ln) * S1 + ks * 32 + quad * 8];
            #pragma unroll
            for (int mt = 0; mt < 4; ++mt)
                #pragma unroll
                for (int nt = 0; nt < 4; ++nt)
                    acc[mt][nt] = __builtin_amdgcn_mfma_f32_16x16x32_bf16(wcur[nt], b[mt], acc[mt][nt], 0, 0, 0);
            #pragma unroll
            for (int nt = 0; nt < 4; ++nt) wcur[nt] = wnxt[nt];
        }
        // issue L3's initial weight frags + bias NOW: latency overlaps the
        // barrier wait + epilogue below (L2 accs die here, so no VGPR peak).
        #pragma unroll
        for (int nt = 0; nt < 4; ++nt)
            v3cur[nt] = *(const short8*)&Wp3T[(nt * 16 + ln) * 256 + quad * 8];
        b3 = *(const float4*)&bp3f[quad * 4];   // lane-invariant in ln; per-nt below

        __syncthreads();   // all h1 reads complete before overwrite
        #pragma unroll
        for (int mt = 0; mt < 4; ++mt)
            #pragma unroll
            for (int nt = 0; nt < 4; ++nt) {
                const floatx4 v = acc[mt][nt];
                uint2 w;
                w.x = pk(fmaxf(v[0], 0.f), fmaxf(v[1], 0.f));
                w.y = pk(fmaxf(v[2], 0.f), fmaxf(v[3], 0.f));
                *(uint2*)&hs[(mt * 16 + ln) * S1 + nb + nt * 16 + quad * 4] = w;
            }
    }
    __syncthreads();

    // ---- layer 3: h3 = h2 @ Wp3 + bp3; lookahead-1 weight prefetch ----
    // h3 overlays the wave's OWN 16-row quarter of hs (DS in-order per wave).
    float* h3f = (float*)&hs[wave * 16 * S1];
    {
        floatx4 acc[4];
        acc[0] = (floatx4){ b3.x, b3.y, b3.z, b3.w };
        #pragma unroll
        for (int nt = 1; nt < 4; ++nt) {
            const float4 bv = *(const float4*)&bp3f[nt * 16 + quad * 4];
            acc[nt] = (floatx4){ bv.x, bv.y, bv.z, bv.w };
        }
        short8 v3nxt[4];
        #pragma unroll
        for (int ks = 0; ks < 8; ++ks) {
            if (ks < 7) {
                #pragma unroll
                for (int nt = 0; nt < 4; ++nt)
                    v3nxt[nt] = *(const short8*)&Wp3T[(nt * 16 + ln) * 256 + (ks + 1) * 32 + quad * 8];
            }
            const short8 b = *(const short8*)&hs[(wave * 16 + ln) * S1 + ks * 32 + quad * 8];
            #pragma unroll
            for (int nt = 0; nt < 4; ++nt)
                acc[nt] = __builtin_amdgcn_mfma_f32_16x16x32_bf16(v3cur[nt], b, acc[nt], 0, 0, 0);
            #pragma unroll
            for (int nt = 0; nt < 4; ++nt) v3cur[nt] = v3nxt[nt];
        }
        #pragma unroll
        for (int nt = 0; nt < 4; ++nt) {
            float4 v = { acc[nt][0], acc[nt][1], acc[nt][2], acc[nt][3] };
            *(float4*)&h3f[ln * SH3 + nt * 16 + quad * 4] = v;   // row=local edge ln
        }
    }

    // ---- scatter: gather LDS into regs first, then run-length combine ----
    {
        const int w0 = wave * 16;
        const int f = lane;                     // feature 0..63
        float rv[16];
        int   rid[16];
        #pragma unroll
        for (int e = 0; e < 16; ++e) {
            rv[e]  = h3f[e * SH3 + f];
            rid[e] = sid[w0 + e];
        }
        int cur = rid[0];
        float local = rv[0];
        #pragma unroll
        for (int e = 1; e < 16; ++e) {
            if (rid[e] == cur) local += rv[e];
            else { atomicAdd(&agg[(long)cur * 64 + f], local); cur = rid[e]; local = rv[e]; }
        }
        atomicAdd(&agg[(long)cur * 64 + f], local);

        if (lane < 2) {
            int c2 = sid[w0];
            float l2 = cb[w0][lane];
            #pragma unroll
            for (int e = 1; e < 16; ++e) {
                const int id = sid[w0 + e];
                const float v = cb[w0 + e][lane];
                if (id == c2) l2 += v;
                else { atomicAdd(&bar[c2 * 2 + lane], l2); c2 = id; l2 = v; }
            }
            atomicAdd(&bar[c2 * 2 + lane], l2);
        }
    }
}

// ---------------------------------------------------------------------------
// Agent MLP, all-MFMA, swapped operands. 32 agents/block, 512 blocks.
// ---------------------------------------------------------------------------
__global__ __launch_bounds__(256, 2) void agent_mlp_kernel(
    const float* __restrict__ agg, const float* __restrict__ bar,
    const short* __restrict__ Wr1T, const float* __restrict__ br1f,
    const short* __restrict__ Wr2T, const float* __restrict__ br2f,
    const float* __restrict__ Wr3f, const float* __restrict__ br3f,
    void* __restrict__ out, const int* __restrict__ flag)
{
    __shared__ __align__(16) short ha[AG * 68];    // bf16 agg (4.4 KB)
    __shared__ __align__(16) short hs[AG * S1];    // r1, then r2 (16.6 KB)
    __shared__ float part[8][AG][2];

    const int t = threadIdx.x;
    const int a0 = blockIdx.x * AG;
    const int f32 = *flag;
    const int wave = t >> 6, lane = t & 63, quad = lane >> 4, ln = lane & 15;
    const int nb = wave * 64;

    #pragma unroll
    for (int i = 0; i < 2; ++i) {
        const float4 x = ((const float4*)agg)[(long)blockIdx.x * 512 + i * 256 + t];
        const int idx4 = (i * 256 + t) * 4;
        s16x4 v = { f2bs(x.x), f2bs(x.y), f2bs(x.z), f2bs(x.w) };
        *(s16x4*)&ha[(idx4 >> 6) * 68 + (idx4 & 63)] = v;
    }
    __syncthreads();

    // ---- r1 = relu(a @ Wr1 + br1), K=64, M=32 ----
    {
        floatx4 acc[2][4];
        #pragma unroll
        for (int nt = 0; nt < 4; ++nt) {
            const float4 bv = *(const float4*)&br1f[nb + nt * 16 + quad * 4];
            const floatx4 bi = { bv.x, bv.y, bv.z, bv.w };
            #pragma unroll
            for (int mt = 0; mt < 2; ++mt) acc[mt][nt] = bi;
        }
        #pragma unroll
        for (int ks = 0; ks < 2; ++ks) {
            short8 b[2], a[4];
            #pragma unroll
            for (int mt = 0; mt < 2; ++mt)
                b[mt] = *(const short8*)&ha[(mt * 16 + ln) * 68 + ks * 32 + quad * 8];
            #pragma unroll
            for (int nt = 0; nt < 4; ++nt)
                a[nt] = *(const short8*)&Wr1T[(nb + nt * 16 + ln) * 64 + ks * 32 + quad * 8];
            #pragma unroll
            for (int mt = 0; mt < 2; ++mt)
                #pragma unroll
                for (int nt = 0; nt < 4; ++nt)
                    acc[mt][nt] = __builtin_amdgcn_mfma_f32_16x16x32_bf16(a[nt], b[mt], acc[mt][nt], 0, 0, 0);
        }
        #pragma unroll
        for (int mt = 0; mt < 2; ++mt)
            #pragma unroll
            for (int nt = 0; nt < 4; ++nt) {
                const floatx4 v = acc[mt][nt];
                uint2 w;
                w.x = pk(fmaxf(v[0], 0.f), fmaxf(v[1], 0.f));
                w.y = pk(fmaxf(v[2], 0.f), fmaxf(v[3], 0.f));
                *(uint2*)&hs[(mt * 16 + ln) * S1 + nb + nt * 16 + quad * 4] = w;
            }
    }
    __syncthreads();

    // ---- r2 = relu(r1 @ Wr2 + br2), K=256, single-buffer ----
    {
        floatx4 acc[2][4];
        #pragma unroll
        for (int nt = 0; nt < 4; ++nt) {
            const float4 bv = *(const float4*)&br2f[nb + nt * 16 + quad * 4];
            const floatx4 bi = { bv.x, bv.y, bv.z, bv.w };
            #pragma unroll
            for (int mt = 0; mt < 2; ++mt) acc[mt][nt] = bi;
        }
        short8 wcur[4], wnxt[4];
        #pragma unroll
        for (int nt = 0; nt < 4; ++nt)
            wcur[nt] = *(const short8*)&Wr2T[(nb + nt * 16 + ln) * 256 + quad * 8];
        #pragma unroll
        for (int ks = 0; ks < 8; ++ks) {
            if (ks < 7) {
                #pragma unroll
                for (int nt = 0; nt < 4; ++nt)
                    wnxt[nt] = *(const short8*)&Wr2T[(nb + nt * 16 + ln) * 256 + (ks + 1) * 32 + quad * 8];
            }
            short8 b[2];
            #pragma unroll
            for (int mt = 0; mt < 2; ++mt)
                b[mt] = *(const short8*)&hs[(mt * 16 + ln) * S1 + ks * 32 + quad * 8];
            #pragma unroll
            for (int mt = 0; mt < 2; ++mt)
                #pragma unroll
                for (int nt = 0; nt < 4; ++nt)
                    acc[mt][nt] = __builtin_amdgcn_mfma_f32_16x16x32_bf16(wcur[nt], b[mt], acc[mt][nt], 0, 0, 0);
            #pragma unroll
            for (int nt = 0; nt < 4; ++nt) wcur[nt] = wnxt[nt];
        }
        __syncthreads();
        #pragma unroll
        for (int mt = 0; mt < 2; ++mt)
            #pragma unroll
            for (int nt = 0; nt < 4; ++nt) {
                const floatx4 v = acc[mt][nt];
                uint2 w;
                w.x = pk(fmaxf(v[0], 0.f), fmaxf(v[1], 0.f));
                w.y = pk(fmaxf(v[2], 0.f), fmaxf(v[3], 0.f));
                *(uint2*)&hs[(mt * 16 + ln) * S1 + nb + nt * 16 + quad * 4] = w;
            }
    }
    __syncthreads();

    // ---- out = r2 @ Wr3 + br3 + bar (N=2, VALU, 8-way K-split) ----
    {
        const int m = t & 31;
        const int p = t >> 5;                     // 8 K-partitions of 32
        float v0 = 0.f, v1 = 0.f;
        #pragma unroll
        for (int kk = 0; kk < 4; ++kk) {
            const int k0 = p * 32 + kk * 8;
            const short8 h = *(const short8*)&hs[m * S1 + k0];
            #pragma unroll
            for (int j = 0; j < 8; ++j) {
                const float hv = bs2f(h[j]);
                v0 = fmaf(hv, Wr3f[(k0 + j) * 2 + 0], v0);
                v1 = fmaf(hv, Wr3f[(k0 + j) * 2 + 1], v1);
            }
        }
        part[p][m][0] = v0;
        part[p][m][1] = v1;
    }
    __syncthreads();
    if (t < 64) {
        const int m = t >> 1, o = t & 1;
        float s = br3f[o] + bar[(long)(a0 + m) * 2 + o];
        #pragma unroll
        for (int p = 0; p < 8; ++p) s += part[p][m][o];
        if (f32) ((float*)out)[(a0 + m) * 2 + o] = s;
        else     ((bf16*)out)[(a0 + m) * 2 + o] = __float2bfloat16(s);
    }
}

extern "C" void kernel_launch(void* const* d_in, const int* in_sizes, int n_in,
                              void* d_out, int out_size, void* d_ws, size_t ws_size,
                              hipStream_t stream)
{
    (void)in_sizes; (void)n_in; (void)out_size;

    const void* ef  = d_in[0];
    const int*  ids = (const int*)d_in[1];

    char* p = (char*)d_ws;
    int*   flag  = (int*)p;        p += 256;
    float* agg   = (float*)p;      p += (size_t)NA * 64 * 4;
    float* bar   = (float*)p;      p += (size_t)NA * 2 * 4;
    short* Wp1Tp = (short*)p;      p += 8192 * 2;
    short* Wp2T  = (short*)p;      p += 65536 * 2;
    short* Wp3T  = (short*)p;      p += 16384 * 2;
    short* Wr1T  = (short*)p;      p += 16384 * 2;
    short* Wr2T  = (short*)p;      p += 65536 * 2;
    float* bp1f  = (float*)p;      p += 256 * 4;
    float* bp2f  = (float*)p;      p += 256 * 4;
    float* bp3f  = (float*)p;      p += 64 * 4;
    float* br1f  = (float*)p;      p += 256 * 4;
    float* br2f  = (float*)p;      p += 256 * 4;
    float* Wr3f  = (float*)p;      p += 512 * 4;
    float* br3f  = (float*)p;      p += 256;
    const size_t required = (size_t)(p - (char*)d_ws);
    if (ws_size < required) return;  // signature: output stays zero (absmax ~26)

    hipMemsetAsync(agg, 0, ((size_t)NA * 64 + (size_t)NA * 2) * 4, stream);
    prep_weights_kernel<<<64, 256, 0, stream>>>(
        d_in[2], d_in[3], d_in[4], d_in[5], d_in[6], d_in[7],
        d_in[8], d_in[9], d_in[10], d_in[11], d_in[12], d_in[13],
        Wp1Tp, Wp2T, Wp3T, Wr1T, Wr2T,
        bp1f, bp2f, bp3f, br1f, br2f, Wr3f, br3f, flag);
    edge_mlp_kernel<<<NE / E, 256, 0, stream>>>(
        ef, ids, Wp1Tp, bp1f, Wp2T, bp2f, Wp3T, bp3f, agg, bar, flag);
    agent_mlp_kernel<<<NA / AG, 256, 0, stream>>>(
        agg, bar, Wr1T, br1f, Wr2T, br2f, Wr3f, br3f, d_out, flag);
}

// Round 8
// 359.389 us; speedup vs baseline: 1.0504x; 1.0504x over previous
//
#include <hip/hip_runtime.h>
#include <hip/hip_bf16.h>

typedef __hip_bfloat16 bf16;
typedef __attribute__((ext_vector_type(8))) short short8;   // MFMA A/B frag (8 bf16)
typedef __attribute__((ext_vector_type(4))) float floatx4;  // MFMA C/D frag
typedef __attribute__((ext_vector_type(4))) short s16x4;

#define NE 524288
#define NA 16384
#define E  64        // edges per block (edge kernel)
#define AG 32        // agents per block (agent kernel)
#define S1 260       // LDS act row stride (shorts)
#define SH3 68       // h3 overlay row stride (floats), inside wave's own quarter

__device__ __forceinline__ float ld(const void* p, long i, int f32) {
    return f32 ? ((const float*)p)[i] : __bfloat162float(((const bf16*)p)[i]);
}
__device__ __forceinline__ short f2bs(float f) {
    bf16 h = __float2bfloat16(f);
    return *(short*)&h;
}
__device__ __forceinline__ float bs2f(short s) {
    union { unsigned u; float f; } c;
    c.u = ((unsigned)(unsigned short)s) << 16;
    return c.f;
}
// pack 2 floats -> 2 bf16 in one dword (a = low/even n, b = high/odd n)
__device__ __forceinline__ unsigned pk(float a, float b) {
    return ((unsigned)(unsigned short)f2bs(b) << 16) | (unsigned)(unsigned short)f2bs(a);
}

// ---------------------------------------------------------------------------
// Weight prep (dtype detector fused in). R8: transposes read CONTIGUOUS
// source indices (coalesced) and scatter the writes (absorbed by L2).
// ---------------------------------------------------------------------------
__global__ void prep_weights_kernel(
    const void* __restrict__ Wp1, const void* __restrict__ bp1,
    const void* __restrict__ Wp2, const void* __restrict__ bp2,
    const void* __restrict__ Wp3, const void* __restrict__ bp3,
    const void* __restrict__ Wr1, const void* __restrict__ br1,
    const void* __restrict__ Wr2, const void* __restrict__ br2,
    const void* __restrict__ Wr3, const void* __restrict__ br3,
    short* __restrict__ Wp1Tp, short* __restrict__ Wp2T, short* __restrict__ Wp3T,
    short* __restrict__ Wr1T,  short* __restrict__ Wr2T,
    float* __restrict__ bp1f, float* __restrict__ bp2f, float* __restrict__ bp3f,
    float* __restrict__ br1f, float* __restrict__ br2f,
    float* __restrict__ Wr3f, float* __restrict__ br3f,
    int* __restrict__ flag)
{
    __shared__ int sflag;
    if (threadIdx.x < 64) {
        const unsigned short* w = (const unsigned short*)Wp2;
        int bad = 0;
        for (int i = threadIdx.x; i < 1024; i += 64) {
            const int e = (w[i] >> 7) & 0xFF;
            if (e >= 131) bad = 1;                // |v|>=16 / inf / nan -> f32 bits
        }
        const unsigned long long m = __ballot(bad);
        if (threadIdx.x == 0) {
            sflag = (m != 0ull) ? 1 : 0;
            if (blockIdx.x == 0) *flag = sflag;
        }
    }
    __syncthreads();
    const int f32 = sflag;

    const int stride = gridDim.x * blockDim.x;
    for (int i = blockIdx.x * blockDim.x + threadIdx.x; i < 173634; i += stride) {
        if (i < 65536) {                       // Wp2: i = k*256+n (coalesced read)
            const int k = i >> 8, n = i & 255;
            Wp2T[n * 256 + k] = f2bs(ld(Wp2, i, f32));
        } else if (i < 81920) {                // Wp3: j = k*64+n (coalesced read)
            const int j = i - 65536, k = j >> 6, n = j & 63;
            Wp3T[n * 256 + k] = f2bs(ld(Wp3, j, f32));
        } else if (i < 90112) {                // Wp1Tp[n][k<32], zero-pad k>=4
            const int j = i - 81920, n = j >> 5, k = j & 31;
            Wp1Tp[j] = (k < 4) ? f2bs(ld(Wp1, (long)k * 256 + n, f32)) : (short)0;
        } else if (i < 106496) {               // Wr1: j = k*256+n (coalesced read)
            const int j = i - 90112, k = j >> 8, n = j & 255;
            Wr1T[n * 64 + k] = f2bs(ld(Wr1, j, f32));
        } else if (i < 172032) {               // Wr2: j = k*256+n (coalesced read)
            const int j = i - 106496, k = j >> 8, n = j & 255;
            Wr2T[n * 256 + k] = f2bs(ld(Wr2, j, f32));
        } else if (i < 172288) { bp1f[i - 172032] = ld(bp1, i - 172032, f32); }
        else if (i < 172544) { bp2f[i - 172288] = ld(bp2, i - 172288, f32); }
        else if (i < 172608) { bp3f[i - 172544] = ld(bp3, i - 172544, f32); }
        else if (i < 172864) { br1f[i - 172608] = ld(br1, i - 172608, f32); }
        else if (i < 173120) { br2f[i - 172864] = ld(br2, i - 172864, f32); }
        else if (i < 173632) { Wr3f[i - 173120] = ld(Wr3, i - 173120, f32); }
        else                 { br3f[i - 173632] = ld(br3, i - 173632, f32); }
    }
}

// ---------------------------------------------------------------------------
// Edge MLP, all-MFMA, swapped operands (weights=A, acts=B). 64 edges/block.
// R8: XCD-swizzled block->edge-tile mapping (each XCD owns one contiguous
// eighth of the edges so each agent's atomics stay in one L2); L3 K-loop
// lookahead-1 weight prefetch with v3cur issued before the L2-epilogue
// barrier (L2's weight regs are dead there -> no register-peak increase).
// ---------------------------------------------------------------------------
__global__ __launch_bounds__(256, 4) void edge_mlp_kernel(
    const void* __restrict__ ef, const int* __restrict__ ids,
    const short* __restrict__ Wp1Tp, const float* __restrict__ bp1f,
    const short* __restrict__ Wp2T, const float* __restrict__ bp2f,
    const short* __restrict__ Wp3T, const float* __restrict__ bp3f,
    float* __restrict__ agg, float* __restrict__ bar,
    const int* __restrict__ flag)
{
    __shared__ __align__(16) short hs[E * S1];     // 33.3 KB: h1, h2, then h3 overlay
    __shared__ float cb[E][2];
    __shared__ int   sid[E];

    const int t = threadIdx.x;
    // XCD swizzle: dispatch round-robins blocks over 8 XCDs; give XCD x the
    // contiguous tile range [x*NB/8, (x+1)*NB/8) so sorted segment ids (and
    // their atomic targets) stay XCD-local. Heuristic only - safe if wrong.
    const int nb8 = gridDim.x >> 3;
    const int blk = (blockIdx.x & 7) * nb8 + (blockIdx.x >> 3);
    const long e0 = (long)blk * E;
    const int f32 = *flag;
    const int wave = t >> 6, lane = t & 63, quad = lane >> 4, ln = lane & 15;
    const int nb = wave * 64;

    if (t < E) {
        sid[t] = ids[e0 + t];
        const float px = ld(ef, (e0 + t) * 4 + 0, f32);
        const float py = ld(ef, (e0 + t) * 4 + 1, f32);
        const float d = sqrtf(px * px + py * py);
        const float inv = 1.0f / (d * (d - 0.18f));
        cb[t][0] = -px * inv;
        cb[t][1] = -py * inv;
    }

    // ---- layer 1: h1 = relu(x @ Wp1 + bp1); A=Wp1^T tiles, B=x frags ----
    {
        short8 b[4];                       // B-operand: edges mt*16+ln (quad 0 holds k<4)
        #pragma unroll
        for (int mt = 0; mt < 4; ++mt) {
            short8 v = {};
            if (quad == 0) {
                const long e = e0 + mt * 16 + ln;
                if (f32) {
                    const float4 x = ((const float4*)ef)[e];
                    v[0] = f2bs(x.x); v[1] = f2bs(x.y); v[2] = f2bs(x.z); v[3] = f2bs(x.w);
                } else {
                    const int2 x = ((const int2*)ef)[e];
                    v[0] = (short)(x.x & 0xffff); v[1] = (short)((unsigned)x.x >> 16);
                    v[2] = (short)(x.y & 0xffff); v[3] = (short)((unsigned)x.y >> 16);
                }
            }
            b[mt] = v;
        }
        floatx4 acc[4][4];                 // [mt][nt], init = bias rows
        #pragma unroll
        for (int nt = 0; nt < 4; ++nt) {
            const float4 bv = *(const float4*)&bp1f[nb + nt * 16 + quad * 4];
            const floatx4 bi = { bv.x, bv.y, bv.z, bv.w };
            #pragma unroll
            for (int mt = 0; mt < 4; ++mt) acc[mt][nt] = bi;
        }
        #pragma unroll
        for (int nt = 0; nt < 4; ++nt) {
            const short8 a = *(const short8*)&Wp1Tp[(nb + nt * 16 + ln) * 32 + quad * 8];
            #pragma unroll
            for (int mt = 0; mt < 4; ++mt)
                acc[mt][nt] = __builtin_amdgcn_mfma_f32_16x16x32_bf16(a, b[mt], acc[mt][nt], 0, 0, 0);
        }
        #pragma unroll
        for (int mt = 0; mt < 4; ++mt)
            #pragma unroll
            for (int nt = 0; nt < 4; ++nt) {
                const floatx4 v = acc[mt][nt];
                uint2 w;
                w.x = pk(fmaxf(v[0], 0.f), fmaxf(v[1], 0.f));
                w.y = pk(fmaxf(v[2], 0.f), fmaxf(v[3], 0.f));
                *(uint2*)&hs[(mt * 16 + ln) * S1 + nb + nt * 16 + quad * 4] = w;
            }
    }
    __syncthreads();

    // ---- layer 2: h2 = relu(h1 @ Wp2 + bp2); A=Wp2^T (prefetched), B=h1 ----
    short8 v3cur[4];     // L3 ks=0 weights, issued before the epilogue barrier
    {
        floatx4 acc[4][4];
        #pragma unroll
        for (int nt = 0; nt < 4; ++nt) {
            const float4 bv = *(const float4*)&bp2f[nb + nt * 16 + quad * 4];
            const floatx4 bi = { bv.x, bv.y, bv.z, bv.w };
            #pragma unroll
            for (int mt = 0; mt < 4; ++mt) acc[mt][nt] = bi;
        }
        short8 wcur[4], wnxt[4];
        #pragma unroll
        for (int nt = 0; nt < 4; ++nt)
            wcur[nt] = *(const short8*)&Wp2T[(nb + nt * 16 + ln) * 256 + quad * 8];
        #pragma unroll
        for (int ks = 0; ks < 8; ++ks) {
            if (ks < 7) {
                #pragma unroll
                for (int nt = 0; nt < 4; ++nt)
                    wnxt[nt] = *(const short8*)&Wp2T[(nb + nt * 16 + ln) * 256 + (ks + 1) * 32 + quad * 8];
            }
            short8 b[4];
            #pragma unroll
            for (int mt = 0; mt < 4; ++mt)
                b[mt] = *(const short8*)&hs[(mt * 16 + ln) * S1 + ks * 32 + quad * 8];
            #pragma unroll
            for (int mt = 0; mt < 4; ++mt)
                #pragma unroll
                for (int nt = 0; nt < 4; ++nt)
                    acc[mt][nt] = __builtin_amdgcn_mfma_f32_16x16x32_bf16(wcur[nt], b[mt], acc[mt][nt], 0, 0, 0);
            #pragma unroll
            for (int nt = 0; nt < 4; ++nt) wcur[nt] = wnxt[nt];
        }
        // issue L3's ks=0 weight frags now: latency overlaps barrier + epilogue;
        // L2's wcur/wnxt are dead here so the register peak does not rise.
        #pragma unroll
        for (int nt = 0; nt < 4; ++nt)
            v3cur[nt] = *(const short8*)&Wp3T[(nt * 16 + ln) * 256 + quad * 8];

        __syncthreads();   // all h1 reads complete before overwrite
        #pragma unroll
        for (int mt = 0; mt < 4; ++mt)
            #pragma unroll
            for (int nt = 0; nt < 4; ++nt) {
                const floatx4 v = acc[mt][nt];
                uint2 w;
                w.x = pk(fmaxf(v[0], 0.f), fmaxf(v[1], 0.f));
                w.y = pk(fmaxf(v[2], 0.f), fmaxf(v[3], 0.f));
                *(uint2*)&hs[(mt * 16 + ln) * S1 + nb + nt * 16 + quad * 4] = w;
            }
    }
    __syncthreads();

    // ---- layer 3: h3 = h2 @ Wp3 + bp3; lookahead-1 weight prefetch ----
    // h3 overlays the wave's OWN 16-row quarter of hs (DS in-order per wave).
    float* h3f = (float*)&hs[wave * 16 * S1];
    {
        floatx4 acc[4];
        #pragma unroll
        for (int nt = 0; nt < 4; ++nt) {
            const float4 bv = *(const float4*)&bp3f[nt * 16 + quad * 4];
            acc[nt] = (floatx4){ bv.x, bv.y, bv.z, bv.w };
        }
        short8 v3nxt[4];
        #pragma unroll
        for (int ks = 0; ks < 8; ++ks) {
            if (ks < 7) {
                #pragma unroll
                for (int nt = 0; nt < 4; ++nt)
                    v3nxt[nt] = *(const short8*)&Wp3T[(nt * 16 + ln) * 256 + (ks + 1) * 32 + quad * 8];
            }
            const short8 b = *(const short8*)&hs[(wave * 16 + ln) * S1 + ks * 32 + quad * 8];
            #pragma unroll
            for (int nt = 0; nt < 4; ++nt)
                acc[nt] = __builtin_amdgcn_mfma_f32_16x16x32_bf16(v3cur[nt], b, acc[nt], 0, 0, 0);
            #pragma unroll
            for (int nt = 0; nt < 4; ++nt) v3cur[nt] = v3nxt[nt];
        }
        #pragma unroll
        for (int nt = 0; nt < 4; ++nt) {
            float4 v = { acc[nt][0], acc[nt][1], acc[nt][2], acc[nt][3] };
            *(float4*)&h3f[ln * SH3 + nt * 16 + quad * 4] = v;   // row=local edge ln
        }
    }

    // ---- scatter: each wave handles its own 16-edge window (ids sorted) ----
    {
        const int w0 = wave * 16;
        const int f = lane;                     // feature 0..63
        int cur = sid[w0];
        float local = h3f[f];
        #pragma unroll
        for (int e = 1; e < 16; ++e) {
            const int id = sid[w0 + e];
            const float v = h3f[e * SH3 + f];
            if (id == cur) local += v;
            else { atomicAdd(&agg[(long)cur * 64 + f], local); cur = id; local = v; }
        }
        atomicAdd(&agg[(long)cur * 64 + f], local);

        if (lane < 2) {
            int c2 = sid[w0];
            float l2 = cb[w0][lane];
            #pragma unroll
            for (int e = 1; e < 16; ++e) {
                const int id = sid[w0 + e];
                const float v = cb[w0 + e][lane];
                if (id == c2) l2 += v;
                else { atomicAdd(&bar[c2 * 2 + lane], l2); c2 = id; l2 = v; }
            }
            atomicAdd(&bar[c2 * 2 + lane], l2);
        }
    }
}

// ---------------------------------------------------------------------------
// Agent MLP, all-MFMA, swapped operands. 32 agents/block, 512 blocks.
// ---------------------------------------------------------------------------
__global__ __launch_bounds__(256, 2) void agent_mlp_kernel(
    const float* __restrict__ agg, const float* __restrict__ bar,
    const short* __restrict__ Wr1T, const float* __restrict__ br1f,
    const short* __restrict__ Wr2T, const float* __restrict__ br2f,
    const float* __restrict__ Wr3f, const float* __restrict__ br3f,
    void* __restrict__ out, const int* __restrict__ flag)
{
    __shared__ __align__(16) short ha[AG * 68];    // bf16 agg (4.4 KB)
    __shared__ __align__(16) short hs[AG * S1];    // r1, then r2 (16.6 KB)
    __shared__ float part[8][AG][2];

    const int t = threadIdx.x;
    const int a0 = blockIdx.x * AG;
    const int f32 = *flag;
    const int wave = t >> 6, lane = t & 63, quad = lane >> 4, ln = lane & 15;
    const int nb = wave * 64;

    #pragma unroll
    for (int i = 0; i < 2; ++i) {
        const float4 x = ((const float4*)agg)[(long)blockIdx.x * 512 + i * 256 + t];
        const int idx4 = (i * 256 + t) * 4;
        s16x4 v = { f2bs(x.x), f2bs(x.y), f2bs(x.z), f2bs(x.w) };
        *(s16x4*)&ha[(idx4 >> 6) * 68 + (idx4 & 63)] = v;
    }
    __syncthreads();

    // ---- r1 = relu(a @ Wr1 + br1), K=64, M=32 ----
    {
        floatx4 acc[2][4];
        #pragma unroll
        for (int nt = 0; nt < 4; ++nt) {
            const float4 bv = *(const float4*)&br1f[nb + nt * 16 + quad * 4];
            const floatx4 bi = { bv.x, bv.y, bv.z, bv.w };
            #pragma unroll
            for (int mt = 0; mt < 2; ++mt) acc[mt][nt] = bi;
        }
        #pragma unroll
        for (int ks = 0; ks < 2; ++ks) {
            short8 b[2], a[4];
            #pragma unroll
            for (int mt = 0; mt < 2; ++mt)
                b[mt] = *(const short8*)&ha[(mt * 16 + ln) * 68 + ks * 32 + quad * 8];
            #pragma unroll
            for (int nt = 0; nt < 4; ++nt)
                a[nt] = *(const short8*)&Wr1T[(nb + nt * 16 + ln) * 64 + ks * 32 + quad * 8];
            #pragma unroll
            for (int mt = 0; mt < 2; ++mt)
                #pragma unroll
                for (int nt = 0; nt < 4; ++nt)
                    acc[mt][nt] = __builtin_amdgcn_mfma_f32_16x16x32_bf16(a[nt], b[mt], acc[mt][nt], 0, 0, 0);
        }
        #pragma unroll
        for (int mt = 0; mt < 2; ++mt)
            #pragma unroll
            for (int nt = 0; nt < 4; ++nt) {
                const floatx4 v = acc[mt][nt];
                uint2 w;
                w.x = pk(fmaxf(v[0], 0.f), fmaxf(v[1], 0.f));
                w.y = pk(fmaxf(v[2], 0.f), fmaxf(v[3], 0.f));
                *(uint2*)&hs[(mt * 16 + ln) * S1 + nb + nt * 16 + quad * 4] = w;
            }
    }
    __syncthreads();

    // ---- r2 = relu(r1 @ Wr2 + br2), K=256, single-buffer ----
    {
        floatx4 acc[2][4];
        #pragma unroll
        for (int nt = 0; nt < 4; ++nt) {
            const float4 bv = *(const float4*)&br2f[nb + nt * 16 + quad * 4];
            const floatx4 bi = { bv.x, bv.y, bv.z, bv.w };
            #pragma unroll
            for (int mt = 0; mt < 2; ++mt) acc[mt][nt] = bi;
        }
        short8 wcur[4], wnxt[4];
        #pragma unroll
        for (int nt = 0; nt < 4; ++nt)
            wcur[nt] = *(const short8*)&Wr2T[(nb + nt * 16 + ln) * 256 + quad * 8];
        #pragma unroll
        for (int ks = 0; ks < 8; ++ks) {
            if (ks < 7) {
                #pragma unroll
                for (int nt = 0; nt < 4; ++nt)
                    wnxt[nt] = *(const short8*)&Wr2T[(nb + nt * 16 + ln) * 256 + (ks + 1) * 32 + quad * 8];
            }
            short8 b[2];
            #pragma unroll
            for (int mt = 0; mt < 2; ++mt)
                b[mt] = *(const short8*)&hs[(mt * 16 + ln) * S1 + ks * 32 + quad * 8];
            #pragma unroll
            for (int mt = 0; mt < 2; ++mt)
                #pragma unroll
                for (int nt = 0; nt < 4; ++nt)
                    acc[mt][nt] = __builtin_amdgcn_mfma_f32_16x16x32_bf16(wcur[nt], b[mt], acc[mt][nt], 0, 0, 0);
            #pragma unroll
            for (int nt = 0; nt < 4; ++nt) wcur[nt] = wnxt[nt];
        }
        __syncthreads();
        #pragma unroll
        for (int mt = 0; mt < 2; ++mt)
            #pragma unroll
            for (int nt = 0; nt < 4; ++nt) {
                const floatx4 v = acc[mt][nt];
                uint2 w;
                w.x = pk(fmaxf(v[0], 0.f), fmaxf(v[1], 0.f));
                w.y = pk(fmaxf(v[2], 0.f), fmaxf(v[3], 0.f));
                *(uint2*)&hs[(mt * 16 + ln) * S1 + nb + nt * 16 + quad * 4] = w;
            }
    }
    __syncthreads();

    // ---- out = r2 @ Wr3 + br3 + bar (N=2, VALU, 8-way K-split) ----
    {
        const int m = t & 31;
        const int p = t >> 5;                     // 8 K-partitions of 32
        float v0 = 0.f, v1 = 0.f;
        #pragma unroll
        for (int kk = 0; kk < 4; ++kk) {
            const int k0 = p * 32 + kk * 8;
            const short8 h = *(const short8*)&hs[m * S1 + k0];
            #pragma unroll
            for (int j = 0; j < 8; ++j) {
                const float hv = bs2f(h[j]);
                v0 = fmaf(hv, Wr3f[(k0 + j) * 2 + 0], v0);
                v1 = fmaf(hv, Wr3f[(k0 + j) * 2 + 1], v1);
            }
        }
        part[p][m][0] = v0;
        part[p][m][1] = v1;
    }
    __syncthreads();
    if (t < 64) {
        const int m = t >> 1, o = t & 1;
        float s = br3f[o] + bar[(long)(a0 + m) * 2 + o];
        #pragma unroll
        for (int p = 0; p < 8; ++p) s += part[p][m][o];
        if (f32) ((float*)out)[(a0 + m) * 2 + o] = s;
        else     ((bf16*)out)[(a0 + m) * 2 + o] = __float2bfloat16(s);
    }
}

extern "C" void kernel_launch(void* const* d_in, const int* in_sizes, int n_in,
                              void* d_out, int out_size, void* d_ws, size_t ws_size,
                              hipStream_t stream)
{
    (void)in_sizes; (void)n_in; (void)out_size;

    const void* ef  = d_in[0];
    const int*  ids = (const int*)d_in[1];

    char* p = (char*)d_ws;
    int*   flag  = (int*)p;        p += 256;
    float* agg   = (float*)p;      p += (size_t)NA * 64 * 4;
    float* bar   = (float*)p;      p += (size_t)NA * 2 * 4;
    short* Wp1Tp = (short*)p;      p += 8192 * 2;
    short* Wp2T  = (short*)p;      p += 65536 * 2;
    short* Wp3T  = (short*)p;      p += 16384 * 2;
    short* Wr1T  = (short*)p;      p += 16384 * 2;
    short* Wr2T  = (short*)p;      p += 65536 * 2;
    float* bp1f  = (float*)p;      p += 256 * 4;
    float* bp2f  = (float*)p;      p += 256 * 4;
    float* bp3f  = (float*)p;      p += 64 * 4;
    float* br1f  = (float*)p;      p += 256 * 4;
    float* br2f  = (float*)p;      p += 256 * 4;
    float* Wr3f  = (float*)p;      p += 512 * 4;
    float* br3f  = (float*)p;      p += 256;
    const size_t required = (size_t)(p - (char*)d_ws);
    if (ws_size < required) return;  // signature: output stays zero (absmax ~26)

    hipMemsetAsync(agg, 0, ((size_t)NA * 64 + (size_t)NA * 2) * 4, stream);
    prep_weights_kernel<<<64, 256, 0, stream>>>(
        d_in[2], d_in[3], d_in[4], d_in[5], d_in[6], d_in[7],
        d_in[8], d_in[9], d_in[10], d_in[11], d_in[12], d_in[13],
        Wp1Tp, Wp2T, Wp3T, Wr1T, Wr2T,
        bp1f, bp2f, bp3f, br1f, br2f, Wr3f, br3f, flag);
    edge_mlp_kernel<<<NE / E, 256, 0, stream>>>(
        ef, ids, Wp1Tp, bp1f, Wp2T, bp2f, Wp3T, bp3f, agg, bar, flag);
    agent_mlp_kernel<<<NA / AG, 256, 0, stream>>>(
        agg, bar, Wr1T, br1f, Wr2T, br2f, Wr3f, br3f, d_out, flag);
}